// Round 3
// baseline (880.639 us; speedup 1.0000x reference)
//
#include <hip/hip_runtime.h>

// SAMMCodebook.encode, round 3: pre-converted bf16 + m97-style MFMA coarse
// (global_load_lds staging, 128x128 tile, BK=32) + worklist-driven exact refine.
//
// z[n] = argmin_k (csq[k] - 2<h_n,c_k>). Coarse scores in bf16 (err std ~0.11),
// DELTA=4 margin (~36 sigma) guarantees containment; ambiguous rows (approx
// runner-up within DELTA) go to a compacted worklist for exact fp32 scoring.

#define D_DIM 1024
#define K_CB  512
#define DELTA 4.0f
#define SENTINEL 0x7FFFu

typedef __attribute__((ext_vector_type(8))) short short8;
typedef __attribute__((ext_vector_type(4))) float floatx4;

// ---- fast-path ws layout ----
#define WS_HB    0ull                 // 128 MB  h in bf16
#define WS_CBB   134217728ull         // 1 MB    cb in bf16
#define WS_CSQ   135266304ull         // 2 KB    ||c||^2
#define WS_SLOT  135268352ull         // 1 MB    per-row candidate slot
#define WS_WL    136316928ull         // 256 KB  worklist rows
#define WS_CNT   136579072ull         // 4 B     worklist count
#define WS_NEED  136579136ull

typedef const unsigned int __attribute__((address_space(1)))* gaddr_t;
typedef unsigned int __attribute__((address_space(3)))* laddr_t;
static __device__ __forceinline__ void async_copy16(const void* g, void* l) {
    __builtin_amdgcn_global_load_lds((gaddr_t)g, (laddr_t)l, 16, 0, 0);
}

static __device__ __forceinline__ unsigned f2bf(float f) {
    unsigned u = __builtin_bit_cast(unsigned, f);
    return (u + 0x7FFFu + ((u >> 16) & 1u)) >> 16;   // round-nearest-even
}

// ---------------- h fp32 -> bf16 ----------------
__global__ __launch_bounds__(256)
void hconv_kernel(const float* __restrict__ h, unsigned short* __restrict__ hb) {
    const size_t i = ((size_t)blockIdx.x * 256 + threadIdx.x) * 8;
    const float4 v0 = *(const float4*)(h + i);
    const float4 v1 = *(const float4*)(h + i + 4);
    uint4 u;
    u.x = f2bf(v0.x) | (f2bf(v0.y) << 16);
    u.y = f2bf(v0.z) | (f2bf(v0.w) << 16);
    u.z = f2bf(v1.x) | (f2bf(v1.y) << 16);
    u.w = f2bf(v1.z) | (f2bf(v1.w) << 16);
    *(uint4*)(hb + i) = u;
}

// ---------------- cb fp32 -> bf16 + csq ----------------
__global__ __launch_bounds__(256)
void prep_kernel(const float* __restrict__ cb, unsigned short* __restrict__ cbb,
                 float* __restrict__ csq) {
    __shared__ float red[4];
    const int k = blockIdx.x, t = threadIdx.x;
    const float4 v = *(const float4*)(cb + (size_t)k * D_DIM + t * 4);
    uint2 u;
    u.x = f2bf(v.x) | (f2bf(v.y) << 16);
    u.y = f2bf(v.z) | (f2bf(v.w) << 16);
    *(uint2*)(cbb + (size_t)k * D_DIM + t * 4) = u;
    float s = v.x * v.x + v.y * v.y + v.z * v.z + v.w * v.w;
    #pragma unroll
    for (int off = 32; off > 0; off >>= 1) s += __shfl_down(s, off, 64);
    if ((t & 63) == 0) red[t >> 6] = s;
    __syncthreads();
    if (t == 0) csq[k] = red[0] + red[1] + red[2] + red[3];
}

// ---------------- coarse: m97-style MFMA GEMM + per-row candidate emit ----------------
__global__ __launch_bounds__(256, 2)
void coarse2_kernel(const unsigned short* __restrict__ hb,
                    const unsigned short* __restrict__ cbb,
                    const float* __restrict__ csq,
                    uint4* __restrict__ slots,
                    int* __restrict__ wl,
                    unsigned* __restrict__ wcount,
                    int* __restrict__ out) {
    __shared__ unsigned char smem[33792] __attribute__((aligned(16)));
    unsigned short* As = (unsigned short*)smem;           // [128][32] bf16, 64B rows
    unsigned short* Bs = (unsigned short*)(smem + 8192);  // [128][32]

    const int tid = threadIdx.x;
    const int w = tid >> 6, lane = tid & 63;
    const int l15 = lane & 15, kq = lane >> 4;
    const int wr = (w >> 1) * 64, wc = (w & 1) * 64;
    const size_t row0 = (size_t)blockIdx.x * 128;

    // staging sources: slot i -> row i>>2, 16B-quad i&3 (dense 64B rows)
    int rS[2], qS[2];
    #pragma unroll
    for (int j = 0; j < 2; ++j) {
        const int slot = j * 256 + w * 64 + lane;
        rS[j] = slot >> 2; qS[j] = slot & 3;
    }
    const unsigned short* gA[2];
    #pragma unroll
    for (int j = 0; j < 2; ++j)
        gA[j] = hb + (row0 + rS[j]) * D_DIM + qS[j] * 8;

    float k1[16], k2[16];
    unsigned cpk[16];
    #pragma unroll
    for (int i = 0; i < 16; ++i) { k1[i] = 3.4e38f; k2[i] = 3.4e38f; cpk[i] = 0; }

    for (int cc = 0; cc < 4; ++cc) {
        floatx4 acc[4][4];
        #pragma unroll
        for (int i = 0; i < 4; ++i)
            #pragma unroll
            for (int j = 0; j < 4; ++j) acc[i][j] = (floatx4){0.f, 0.f, 0.f, 0.f};

        const unsigned short* gB[2];
        #pragma unroll
        for (int j = 0; j < 2; ++j)
            gB[j] = cbb + (size_t)(cc * 128 + rS[j]) * D_DIM + qS[j] * 8;

        #pragma unroll 2
        for (int dk = 0; dk < D_DIM; dk += 32) {
            #pragma unroll
            for (int j = 0; j < 2; ++j) {
                const size_t lds_off = (size_t)(j * 256 + w * 64) * 8;  // shorts
                async_copy16(gA[j] + dk, As + lds_off);
                async_copy16(gB[j] + dk, Bs + lds_off);
            }
            __syncthreads();
            short8 a[4], b[4];
            #pragma unroll
            for (int rt = 0; rt < 4; ++rt)
                a[rt] = *(const short8*)(As + (wr + rt * 16 + l15) * 32 + kq * 8);
            #pragma unroll
            for (int ct = 0; ct < 4; ++ct)
                b[ct] = *(const short8*)(Bs + (wc + ct * 16 + l15) * 32 + kq * 8);
            #pragma unroll
            for (int rt = 0; rt < 4; ++rt)
                #pragma unroll
                for (int ct = 0; ct < 4; ++ct)
                    acc[rt][ct] = __builtin_amdgcn_mfma_f32_16x16x32_bf16(
                        a[rt], b[ct], acc[rt][ct], 0, 0, 0);
            __syncthreads();
        }

        // fold into running top-2 per (row-cell)
        #pragma unroll
        for (int ct = 0; ct < 4; ++ct) {
            const int col = cc * 128 + wc + ct * 16 + l15;
            const float cq = csq[col];
            #pragma unroll
            for (int rt = 0; rt < 4; ++rt)
                #pragma unroll
                for (int reg = 0; reg < 4; ++reg) {
                    const float s = fmaf(-2.0f, acc[rt][ct][reg], cq);
                    const int ri = rt * 4 + reg;
                    if (s < k1[ri]) {
                        k2[ri] = k1[ri]; k1[ri] = s;
                        cpk[ri] = (cpk[ri] << 16) | (unsigned)col;
                    } else if (s < k2[ri]) {
                        k2[ri] = s;
                        cpk[ri] = (cpk[ri] & 0xFFFFu) | ((unsigned)col << 16);
                    }
                }
        }
    }

    // merge 64 entries/row via LDS, two passes of 64 rows
    float* mval = (float*)smem;
    int*   mcol = (int*)(smem + 16896);
    for (int p = 0; p < 2; ++p) {
        __syncthreads();
        if ((w >> 1) == p) {
            #pragma unroll
            for (int rt = 0; rt < 4; ++rt)
                #pragma unroll
                for (int reg = 0; reg < 4; ++reg) {
                    const int ri = rt * 4 + reg;
                    const int rl = rt * 16 + kq * 4 + reg;
                    const int e = ((w & 1) * 16 + l15) * 2;
                    mval[rl * 66 + e] = k1[ri];
                    mcol[rl * 66 + e] = (int)(cpk[ri] & 0xFFFFu);
                    mval[rl * 66 + e + 1] = k2[ri];
                    mcol[rl * 66 + e + 1] = (int)(cpk[ri] >> 16);
                }
        }
        __syncthreads();
        if (tid < 64) {
            const int r = tid;
            float bv = mval[r * 66]; int bc = mcol[r * 66];
            for (int e = 1; e < 64; ++e) {
                const float v = mval[r * 66 + e];
                const int   c = mcol[r * 66 + e];
                if (v < bv || (v == bv && c < bc)) { bv = v; bc = c; }
            }
            const float thr = bv + DELTA;
            unsigned cd[4] = {0, 0, 0, 0};
            int others = 0;
            for (int e = 0; e < 64; ++e) {
                const float v = mval[r * 66 + e];
                const int   c = mcol[r * 66 + e];
                if (v < thr && c != bc) {
                    if (others < 4) cd[others] = (unsigned)c;
                    ++others;
                }
            }
            const size_t grow = row0 + (size_t)p * 64 + r;
            if (others == 0) {
                out[grow] = bc;
            } else {
                const unsigned cnt = (others > 4) ? SENTINEL : (unsigned)(1 + others);
                uint4 s;
                s.x = __builtin_bit_cast(unsigned, bv);
                s.y = (unsigned)bc | (cnt << 16);
                s.z = cd[0] | (cd[1] << 16);
                s.w = cd[2] | (cd[3] << 16);
                slots[grow] = s;
                wl[atomicAdd(wcount, 1u)] = (int)grow;
            }
        }
    }
}

// ---------------- refine: exact fp32 on worklist rows ----------------
__global__ __launch_bounds__(256)
void refine2_kernel(const float* __restrict__ h, const float* __restrict__ cb,
                    const float* __restrict__ csq, const uint4* __restrict__ slots,
                    const int* __restrict__ wl, const unsigned* __restrict__ wcount,
                    int* __restrict__ out) {
    const int w = threadIdx.x >> 6, lane = threadIdx.x & 63;
    const unsigned total = *wcount;
    for (unsigned idx = blockIdx.x * 4 + w; idx < total; idx += 1024) {
        const size_t row = (size_t)wl[idx];
        const uint4 s = slots[row];
        const unsigned cnt = s.y >> 16;
        const bool full = (cnt == SENTINEL);
        int cl[5]; int nc = 0;
        if (!full) {
            nc = (int)cnt;
            cl[0] = (int)(s.y & 0xFFFFu);
            const unsigned cds[4] = {s.z & 0xFFFFu, s.z >> 16, s.w & 0xFFFFu, s.w >> 16};
            for (int i = 1; i < nc; ++i) cl[i] = (int)cds[i - 1];
        }
        const float* hrow = h + row * D_DIM;
        float4 hv[4];
        #pragma unroll
        for (int j = 0; j < 4; ++j)
            hv[j] = *(const float4*)(hrow + j * 256 + lane * 4);
        float bs = 3.4e38f; int bc = 0x7fffffff;
        const int tot = full ? K_CB : nc;
        for (int i = 0; i < tot; ++i) {
            const int c = full ? i : cl[i];
            const float* crow = cb + (size_t)c * D_DIM;
            float d = 0.0f;
            #pragma unroll
            for (int j = 0; j < 4; ++j) {
                const float4 cv = *(const float4*)(crow + j * 256 + lane * 4);
                d = fmaf(hv[j].x, cv.x, d);
                d = fmaf(hv[j].y, cv.y, d);
                d = fmaf(hv[j].z, cv.z, d);
                d = fmaf(hv[j].w, cv.w, d);
            }
            #pragma unroll
            for (int off = 32; off > 0; off >>= 1) d += __shfl_down(d, off, 64);
            d = __shfl(d, 0, 64);
            const float sc = fmaf(-2.0f, d, csq[c]);
            if (sc < bs || (sc == bs && c < bc)) { bs = sc; bc = c; }
        }
        if (lane == 0) out[row] = bc;
    }
}

// ================= R2 fallback (small ws) =================
#define STRIDE 72
__global__ __launch_bounds__(256)
void coarse_kernel(const float* __restrict__ h,
                   const unsigned short* __restrict__ cbb,
                   const float* __restrict__ csq,
                   uint4* __restrict__ slots) {
    __shared__ unsigned char smem[46080] __attribute__((aligned(16)));
    unsigned short* hs = (unsigned short*)smem;
    unsigned short* cs = (unsigned short*)(smem + 64 * STRIDE * 2);
    const int tid = threadIdx.x;
    const int w = tid >> 6, lane = tid & 63;
    const int l15 = lane & 15, kq = lane >> 4;
    const int rowblk = blockIdx.x >> 1, half = blockIdx.x & 1;
    const size_t row0 = (size_t)rowblk * 64;
    const int col0 = half * 256;
    const int wr = (w >> 1) * 32, wc = (w & 1) * 128;
    floatx4 acc[2][8];
    #pragma unroll
    for (int i = 0; i < 2; ++i)
        #pragma unroll
        for (int j = 0; j < 8; ++j) acc[i][j] = (floatx4){0.f, 0.f, 0.f, 0.f};
    for (int dk = 0; dk < D_DIM; dk += 64) {
        #pragma unroll
        for (int p = 0; p < 4; ++p) {
            const int f = p * 256 + tid;
            const int r = f >> 4, c4 = f & 15;
            const float4 v = *(const float4*)(h + (row0 + r) * D_DIM + dk + c4 * 4);
            uint2 u;
            u.x = f2bf(v.x) | (f2bf(v.y) << 16);
            u.y = f2bf(v.z) | (f2bf(v.w) << 16);
            *(uint2*)(hs + r * STRIDE + c4 * 4) = u;
        }
        #pragma unroll
        for (int p = 0; p < 8; ++p) {
            const int f = p * 256 + tid;
            const int cr = f >> 3, g = f & 7;
            const uint4 u = *(const uint4*)(cbb + (size_t)(col0 + cr) * D_DIM + dk + g * 8);
            *(uint4*)(cs + cr * STRIDE + g * 8) = u;
        }
        __syncthreads();
        #pragma unroll
        for (int ks = 0; ks < 64; ks += 32) {
            short8 a[2], b[8];
            #pragma unroll
            for (int rt = 0; rt < 2; ++rt)
                a[rt] = *(const short8*)(hs + (wr + rt * 16 + l15) * STRIDE + ks + kq * 8);
            #pragma unroll
            for (int ct = 0; ct < 8; ++ct)
                b[ct] = *(const short8*)(cs + (wc + ct * 16 + l15) * STRIDE + ks + kq * 8);
            #pragma unroll
            for (int rt = 0; rt < 2; ++rt)
                #pragma unroll
                for (int ct = 0; ct < 8; ++ct)
                    acc[rt][ct] = __builtin_amdgcn_mfma_f32_16x16x32_bf16(
                        a[rt], b[ct], acc[rt][ct], 0, 0, 0);
        }
        __syncthreads();
    }
    float k1[8], k2[8]; int c1[8], c2[8];
    #pragma unroll
    for (int i = 0; i < 8; ++i) { k1[i] = 3.4e38f; k2[i] = 3.4e38f; c1[i] = 0; c2[i] = 0; }
    #pragma unroll
    for (int ct = 0; ct < 8; ++ct) {
        const int col = col0 + wc + ct * 16 + l15;
        const float cq = csq[col];
        #pragma unroll
        for (int rt = 0; rt < 2; ++rt)
            #pragma unroll
            for (int reg = 0; reg < 4; ++reg) {
                const float s = fmaf(-2.0f, acc[rt][ct][reg], cq);
                const int ri = rt * 4 + reg;
                if (s < k1[ri]) { k2[ri] = k1[ri]; c2[ri] = c1[ri]; k1[ri] = s; c1[ri] = col; }
                else if (s < k2[ri]) { k2[ri] = s; c2[ri] = col; }
            }
    }
    float* mval = (float*)smem;
    int*   mcol = (int*)(smem + 64 * 66 * 4);
    __syncthreads();
    #pragma unroll
    for (int rt = 0; rt < 2; ++rt)
        #pragma unroll
        for (int reg = 0; reg < 4; ++reg) {
            const int ri = rt * 4 + reg;
            const int r = wr + rt * 16 + kq * 4 + reg;
            const int e = ((w & 1) * 16 + l15) * 2;
            mval[r * 66 + e] = k1[ri];     mcol[r * 66 + e] = c1[ri];
            mval[r * 66 + e + 1] = k2[ri]; mcol[r * 66 + e + 1] = c2[ri];
        }
    __syncthreads();
    if (tid < 64) {
        const int r = tid;
        float bv = 3.4e38f; int bc = 0x7fffffff;
        for (int e = 0; e < 64; ++e) {
            const float v = mval[r * 66 + e];
            const int   c = mcol[r * 66 + e];
            if (v < bv || (v == bv && c < bc)) { bv = v; bc = c; }
        }
        const float thr = bv + DELTA;
        unsigned cd[4] = {0, 0, 0, 0};
        int others = 0;
        for (int e = 0; e < 64; ++e) {
            const float v = mval[r * 66 + e];
            const int   c = mcol[r * 66 + e];
            if (v < thr && c != bc) {
                if (others < 4) cd[others] = (unsigned)c;
                ++others;
            }
        }
        unsigned cnt = (others > 4) ? SENTINEL : (unsigned)(1 + others);
        uint4 s;
        s.x = __builtin_bit_cast(unsigned, bv);
        s.y = (unsigned)bc | (cnt << 16);
        s.z = cd[0] | (cd[1] << 16);
        s.w = cd[2] | (cd[3] << 16);
        slots[(row0 + r) * 2 + half] = s;
    }
}

__global__ __launch_bounds__(256)
void refine_kernel(const float* __restrict__ h, const float* __restrict__ cb,
                   const float* __restrict__ csq, const uint4* __restrict__ slots,
                   int* __restrict__ out) {
    const int w = threadIdx.x >> 6, lane = threadIdx.x & 63;
    const size_t row = (size_t)blockIdx.x * 4 + w;
    const uint4 s0 = slots[row * 2 + 0];
    const uint4 s1 = slots[row * 2 + 1];
    const float bv0 = __builtin_bit_cast(float, s0.x);
    const float bv1 = __builtin_bit_cast(float, s1.x);
    const float thr = fminf(bv0, bv1) + DELTA;
    int cl[10]; int nc = 0; bool full = false;
    {
        const uint4 ss[2] = {s0, s1};
        const float bvh[2] = {bv0, bv1};
        for (int hh = 0; hh < 2; ++hh) {
            if (!(bvh[hh] < thr)) continue;
            const unsigned cnt = ss[hh].y >> 16;
            if (cnt == SENTINEL) { full = true; continue; }
            cl[nc++] = (int)(ss[hh].y & 0xFFFFu);
            const unsigned cds[4] = {ss[hh].z & 0xFFFFu, ss[hh].z >> 16,
                                     ss[hh].w & 0xFFFFu, ss[hh].w >> 16};
            for (unsigned i = 0; i + 1 < cnt; ++i) cl[nc++] = (int)cds[i];
        }
    }
    if (!full && nc == 1) { if (lane == 0) out[row] = cl[0]; return; }
    const float* hrow = h + row * D_DIM;
    float4 hv[4];
    #pragma unroll
    for (int j = 0; j < 4; ++j) hv[j] = *(const float4*)(hrow + j * 256 + lane * 4);
    float bs = 3.4e38f; int bc = 0x7fffffff;
    const int total = full ? K_CB : nc;
    for (int i = 0; i < total; ++i) {
        const int c = full ? i : cl[i];
        const float* crow = cb + (size_t)c * D_DIM;
        float d = 0.0f;
        #pragma unroll
        for (int j = 0; j < 4; ++j) {
            const float4 cv = *(const float4*)(crow + j * 256 + lane * 4);
            d = fmaf(hv[j].x, cv.x, d);
            d = fmaf(hv[j].y, cv.y, d);
            d = fmaf(hv[j].z, cv.z, d);
            d = fmaf(hv[j].w, cv.w, d);
        }
        #pragma unroll
        for (int off = 32; off > 0; off >>= 1) d += __shfl_down(d, off, 64);
        d = __shfl(d, 0, 64);
        const float sc = fmaf(-2.0f, d, csq[c]);
        if (sc < bs || (sc == bs && c < bc)) { bs = sc; bc = c; }
    }
    if (lane == 0) out[row] = bc;
}

extern "C" void kernel_launch(void* const* d_in, const int* in_sizes, int n_in,
                              void* d_out, int out_size, void* d_ws, size_t ws_size,
                              hipStream_t stream) {
    const float* h  = (const float*)d_in[0];
    const float* cb = (const float*)d_in[1];
    int* out = (int*)d_out;
    unsigned char* ws = (unsigned char*)d_ws;
    const int nrows = in_sizes[0] / D_DIM;   // 65536

    if (ws_size >= WS_NEED) {
        unsigned short* hb  = (unsigned short*)(ws + WS_HB);
        unsigned short* cbb = (unsigned short*)(ws + WS_CBB);
        float* csq   = (float*)(ws + WS_CSQ);
        uint4* slots = (uint4*)(ws + WS_SLOT);
        int*   wl    = (int*)(ws + WS_WL);
        unsigned* wc = (unsigned*)(ws + WS_CNT);
        hipMemsetAsync(wc, 0, 4, stream);
        hconv_kernel<<<dim3((nrows * (D_DIM / 8)) / 256), dim3(256), 0, stream>>>(h, hb);
        prep_kernel<<<dim3(K_CB), dim3(256), 0, stream>>>(cb, cbb, csq);
        coarse2_kernel<<<dim3(nrows / 128), dim3(256), 0, stream>>>(
            hb, cbb, csq, slots, wl, wc, out);
        refine2_kernel<<<dim3(256), dim3(256), 0, stream>>>(
            h, cb, csq, slots, wl, wc, out);
    } else {
        unsigned short* cbb = (unsigned short*)ws;
        float* csq   = (float*)(ws + 1048576);
        uint4* slots = (uint4*)(ws + 1048576 + 2048);
        prep_kernel<<<dim3(K_CB), dim3(256), 0, stream>>>(cb, cbb, csq);
        coarse_kernel<<<dim3((nrows / 64) * 2), dim3(256), 0, stream>>>(h, cbb, csq, slots);
        refine_kernel<<<dim3(nrows / 4), dim3(256), 0, stream>>>(h, cb, csq, slots, out);
    }
}

// Round 4
// 482.188 us; speedup vs baseline: 1.8263x; 1.8263x over previous
//
#include <hip/hip_runtime.h>

// SAMMCodebook.encode, round 4: single-pass fused coarse (64 rows x 512 cols
// per block, in-register fp32->bf16 A conversion, global_load_lds B staging)
// + fully-parallel per-row exact fp32 fixup on ambiguous rows only.
//
// z[n] = argmin_k (csq[k] - 2<h_n,c_k>). bf16 score error std ~0.1; DELTA=4
// (~40 sigma) margin guarantees the true argmin is among the candidates.

#define D_DIM 1024
#define K_CB  512
#define DELTA 4.0f
#define MAXC  8
#define SENT  0xFFFFu

typedef __attribute__((ext_vector_type(8))) short short8;
typedef __attribute__((ext_vector_type(4))) float floatx4;

// ws layout (~3.4 MB)
#define WS_CBB  0ull           // 1 MB   cb bf16
#define WS_CSQ  1048576ull     // 2 KB   ||c||^2
#define WS_SLOT 1050624ull     // 2 MB   65536 x 32B candidate slots
#define WS_WL   3147776ull     // 256 KB worklist
#define WS_CNT  3409920ull     // 4 B    worklist count

typedef const unsigned int __attribute__((address_space(1)))* gaddr_t;
typedef unsigned int __attribute__((address_space(3)))* laddr_t;
static __device__ __forceinline__ void async_copy16(const void* g, void* l) {
    __builtin_amdgcn_global_load_lds((gaddr_t)g, (laddr_t)l, 16, 0, 0);
}

static __device__ __forceinline__ unsigned f2bf(float f) {
    unsigned u = __builtin_bit_cast(unsigned, f);
    return (u + 0x7FFFu + ((u >> 16) & 1u)) >> 16;   // round-nearest-even
}

// ---------------- cb fp32 -> bf16 + csq ----------------
__global__ __launch_bounds__(256)
void prep_kernel(const float* __restrict__ cb, unsigned short* __restrict__ cbb,
                 float* __restrict__ csq) {
    __shared__ float red[4];
    const int k = blockIdx.x, t = threadIdx.x;
    const float4 v = *(const float4*)(cb + (size_t)k * D_DIM + t * 4);
    uint2 u;
    u.x = f2bf(v.x) | (f2bf(v.y) << 16);
    u.y = f2bf(v.z) | (f2bf(v.w) << 16);
    *(uint2*)(cbb + (size_t)k * D_DIM + t * 4) = u;
    float s = v.x * v.x + v.y * v.y + v.z * v.z + v.w * v.w;
    #pragma unroll
    for (int off = 32; off > 0; off >>= 1) s += __shfl_down(s, off, 64);
    if ((t & 63) == 0) red[t >> 6] = s;
    __syncthreads();
    if (t == 0) csq[k] = red[0] + red[1] + red[2] + red[3];
}

// ---------------- coarse: 64x512 per block, full decision ----------------
__global__ __launch_bounds__(256, 2)
void coarse_kernel(const float* __restrict__ h,
                   const unsigned short* __restrict__ cbb,
                   const float* __restrict__ csq,
                   uint4* __restrict__ slots,
                   int* __restrict__ wl,
                   unsigned* __restrict__ wcount,
                   int* __restrict__ out) {
    __shared__ unsigned char smem[66560] __attribute__((aligned(16)));
    unsigned short* As = (unsigned short*)smem;            // [64][32] bf16
    unsigned short* Bs = (unsigned short*)(smem + 4096);   // [512][32] bf16

    const int tid = threadIdx.x;
    const int w = tid >> 6, lane = tid & 63;
    const int l15 = lane & 15, kq = lane >> 4;
    const size_t row0 = (size_t)blockIdx.x * 64;
    const int wc_ = w * 128;                 // wave's 128-col range

    // A staging: thread -> row tid>>2, 8 d-elems at (tid&3)*8
    const int ar = tid >> 2, adq = (tid & 3) * 8;
    const float* gA = h + (row0 + ar) * D_DIM + adq;
    // B staging: copy j covers slot = j*256 + tid; row = j*64 + (tid>>2)
    const unsigned short* gB0 = cbb + (size_t)(tid >> 2) * D_DIM + (tid & 3) * 8;
    unsigned short* ldsB0 = Bs + (size_t)(w * 64 + (lane)) * 0;  // (base below)

    floatx4 acc[4][8];
    #pragma unroll
    for (int i = 0; i < 4; ++i)
        #pragma unroll
        for (int j = 0; j < 8; ++j) acc[i][j] = (floatx4){0.f, 0.f, 0.f, 0.f};

    for (int dk = 0; dk < D_DIM; dk += 32) {
        // B: 8 x global_load_lds dwordx4 (wave-uniform base + lane*16)
        #pragma unroll
        for (int j = 0; j < 8; ++j)
            async_copy16(gB0 + (size_t)j * 64 * D_DIM + dk,
                         Bs + (size_t)(j * 256 + w * 64) * 8);
        // A: fp32 load + convert + one ds_write_b128
        const float4 v0 = *(const float4*)(gA + dk);
        const float4 v1 = *(const float4*)(gA + dk + 4);
        uint4 u;
        u.x = f2bf(v0.x) | (f2bf(v0.y) << 16);
        u.y = f2bf(v0.z) | (f2bf(v0.w) << 16);
        u.z = f2bf(v1.x) | (f2bf(v1.y) << 16);
        u.w = f2bf(v1.z) | (f2bf(v1.w) << 16);
        *(uint4*)(As + ar * 32 + adq) = u;
        __syncthreads();

        short8 a[4], b[8];
        #pragma unroll
        for (int rt = 0; rt < 4; ++rt)
            a[rt] = *(const short8*)(As + (rt * 16 + l15) * 32 + kq * 8);
        #pragma unroll
        for (int ct = 0; ct < 8; ++ct)
            b[ct] = *(const short8*)(Bs + (wc_ + ct * 16 + l15) * 32 + kq * 8);
        #pragma unroll
        for (int rt = 0; rt < 4; ++rt)
            #pragma unroll
            for (int ct = 0; ct < 8; ++ct)
                acc[rt][ct] = __builtin_amdgcn_mfma_f32_16x16x32_bf16(
                    a[rt], b[ct], acc[rt][ct], 0, 0, 0);
        __syncthreads();
    }

    // fold: per-lane top-2 per row-reg (cell = 8 cols)
    float k1[16], k2[16];
    unsigned cpk[16];
    #pragma unroll
    for (int i = 0; i < 16; ++i) { k1[i] = 3.4e38f; k2[i] = 3.4e38f; cpk[i] = 0; }
    #pragma unroll
    for (int ct = 0; ct < 8; ++ct) {
        const int col = wc_ + ct * 16 + l15;
        const float cq = csq[col];
        #pragma unroll
        for (int rt = 0; rt < 4; ++rt)
            #pragma unroll
            for (int reg = 0; reg < 4; ++reg) {
                const float s = fmaf(-2.0f, acc[rt][ct][reg], cq);
                const int ri = rt * 4 + reg;
                if (s < k1[ri]) {
                    k2[ri] = k1[ri]; k1[ri] = s;
                    cpk[ri] = (cpk[ri] << 16) | (unsigned)col;
                } else if (s < k2[ri]) {
                    k2[ri] = s;
                    cpk[ri] = (cpk[ri] & 0xFFFFu) | ((unsigned)col << 16);
                }
            }
    }

    // merge: 128 entries per row (4 waves x 16 lanes x top2) via LDS
    float* mval = (float*)smem;                    // [64][130]
    int*   mcol = (int*)(smem + 33280);            // [64][130]
    __syncthreads();
    #pragma unroll
    for (int rt = 0; rt < 4; ++rt)
        #pragma unroll
        for (int reg = 0; reg < 4; ++reg) {
            const int ri = rt * 4 + reg;
            const int r = rt * 16 + kq * 4 + reg;
            const int e = (w * 16 + l15) * 2;
            mval[r * 130 + e] = k1[ri];
            mcol[r * 130 + e] = (int)(cpk[ri] & 0xFFFFu);
            mval[r * 130 + e + 1] = k2[ri];
            mcol[r * 130 + e + 1] = (int)(cpk[ri] >> 16);
        }
    __syncthreads();

    if (tid < 64) {
        const int r = tid;
        float bv = mval[r * 130]; int bc = mcol[r * 130];
        for (int e = 1; e < 128; ++e) {
            const float v = mval[r * 130 + e];
            const int   c = mcol[r * 130 + e];
            if (v < bv || (v == bv && c < bc)) { bv = v; bc = c; }
        }
        const float thr = bv + DELTA;
        unsigned cd[MAXC] = {0, 0, 0, 0, 0, 0, 0, 0};
        int others = 0;
        for (int e = 0; e < 128; ++e) {
            const float v = mval[r * 130 + e];
            const int   c = mcol[r * 130 + e];
            if (v < thr && c != bc) {
                if (others < MAXC) cd[others] = (unsigned)c;
                ++others;
            }
        }
        const size_t grow = row0 + r;
        if (others == 0) {
            out[grow] = bc;            // unambiguous: approx winner is exact
        } else {
            const unsigned cnt = (others > MAXC) ? SENT : (unsigned)others;
            uint4 s0, s1;
            s0.x = __builtin_bit_cast(unsigned, bv);
            s0.y = (unsigned)bc | (cnt << 16);
            s0.z = cd[0] | (cd[1] << 16);
            s0.w = cd[2] | (cd[3] << 16);
            s1.x = cd[4] | (cd[5] << 16);
            s1.y = cd[6] | (cd[7] << 16);
            s1.z = 0; s1.w = 0;
            slots[grow * 2] = s0;
            slots[grow * 2 + 1] = s1;
            wl[atomicAdd(wcount, 1u)] = (int)grow;
        }
    }
}

// ---------------- fixup: exact fp32, one wave per ambiguous row ----------------
__global__ __launch_bounds__(256)
void fixup_kernel(const float* __restrict__ h, const float* __restrict__ cb,
                  const float* __restrict__ csq, const uint4* __restrict__ slots,
                  const int* __restrict__ wl, const unsigned* __restrict__ wcount,
                  int* __restrict__ out) {
    const int w = threadIdx.x >> 6, lane = threadIdx.x & 63;
    const unsigned idx = blockIdx.x * 4 + w;
    if (idx >= *wcount) return;
    const size_t row = (size_t)wl[idx];
    const uint4 s0 = slots[row * 2];
    const uint4 s1 = slots[row * 2 + 1];
    const unsigned cnt = s0.y >> 16;
    const bool full = (cnt == SENT);
    int cl[1 + MAXC]; int nc = 0;
    if (!full) {
        cl[0] = (int)(s0.y & 0xFFFFu);
        const unsigned cds[MAXC] = {s0.z & 0xFFFFu, s0.z >> 16, s0.w & 0xFFFFu, s0.w >> 16,
                                    s1.x & 0xFFFFu, s1.x >> 16, s1.y & 0xFFFFu, s1.y >> 16};
        nc = 1 + (int)cnt;
        #pragma unroll
        for (int i = 0; i < MAXC; ++i)
            if (i < (int)cnt) cl[1 + i] = (int)cds[i];
    }

    const float* hrow = h + row * D_DIM;
    float4 hv[4];
    #pragma unroll
    for (int j = 0; j < 4; ++j)
        hv[j] = *(const float4*)(hrow + j * 256 + lane * 4);

    float bs = 3.4e38f; int bc = 0x7fffffff;
    const int total = full ? K_CB : nc;
    for (int i = 0; i < total; ++i) {
        const int c = full ? i : cl[i];
        const float* crow = cb + (size_t)c * D_DIM;
        float d = 0.0f;
        #pragma unroll
        for (int j = 0; j < 4; ++j) {
            const float4 cv = *(const float4*)(crow + j * 256 + lane * 4);
            d = fmaf(hv[j].x, cv.x, d);
            d = fmaf(hv[j].y, cv.y, d);
            d = fmaf(hv[j].z, cv.z, d);
            d = fmaf(hv[j].w, cv.w, d);
        }
        #pragma unroll
        for (int off = 32; off > 0; off >>= 1) d += __shfl_down(d, off, 64);
        d = __shfl(d, 0, 64);
        const float sc = fmaf(-2.0f, d, csq[c]);
        if (sc < bs || (sc == bs && c < bc)) { bs = sc; bc = c; }
    }
    if (lane == 0) out[row] = bc;
}

extern "C" void kernel_launch(void* const* d_in, const int* in_sizes, int n_in,
                              void* d_out, int out_size, void* d_ws, size_t ws_size,
                              hipStream_t stream) {
    const float* h  = (const float*)d_in[0];
    const float* cb = (const float*)d_in[1];
    int* out = (int*)d_out;
    unsigned char* ws = (unsigned char*)d_ws;
    const int nrows = in_sizes[0] / D_DIM;   // 65536

    unsigned short* cbb = (unsigned short*)(ws + WS_CBB);
    float* csq   = (float*)(ws + WS_CSQ);
    uint4* slots = (uint4*)(ws + WS_SLOT);
    int*   wl    = (int*)(ws + WS_WL);
    unsigned* wc = (unsigned*)(ws + WS_CNT);

    hipMemsetAsync(wc, 0, 4, stream);
    prep_kernel<<<dim3(K_CB), dim3(256), 0, stream>>>(cb, cbb, csq);
    coarse_kernel<<<dim3(nrows / 64), dim3(256), 0, stream>>>(
        h, cbb, csq, slots, wl, wc, out);
    fixup_kernel<<<dim3(nrows / 4), dim3(256), 0, stream>>>(
        h, cb, csq, slots, wl, wc, out);
}